// Round 2
// baseline (64.703 us; speedup 1.0000x reference)
//
#include <hip/hip_runtime.h>

// InterAgentSoftPenalty: B=32, H=256, N=64, D=4N=256.
// pos[b,h,n,:] = states[b,h,n*4 + {0,1}]; out[b,h] = 10 * sum_{i>j} exp(-d2/0.01)
//
// One wave (64 lanes) per (b,h) row. Lane i holds pos_i (loaded as float4 —
// fully coalesced, 16B/lane covers the whole 256-float row). Broadcast pos_j
// with v_readlane (uniform SGPR), accumulate exp2(-d2*c) over ALL 64x64 pairs
// (diagonal contributes exp(0)=1 each), then strict-lower sum = (S - 64)/2.

#ifndef __has_builtin
#define __has_builtin(x) 0
#endif

__device__ __forceinline__ float fast_exp2(float x) {
#if __has_builtin(__builtin_amdgcn_exp2f)
    return __builtin_amdgcn_exp2f(x);
#else
    return exp2f(x);
#endif
}

__global__ __launch_bounds__(256) void inter_agent_penalty_kernel(
    const float* __restrict__ states,  // [total][256] = [total][64 agents][4]
    float* __restrict__ out,           // [total]
    int total) {
    const int gtid = blockIdx.x * blockDim.x + threadIdx.x;
    const int wave = gtid >> 6;
    const int lane = threadIdx.x & 63;
    if (wave >= total) return;

    // Coalesced load: lane i reads float4 #i of this row; (x,y) = first two.
    const float4 v = reinterpret_cast<const float4*>(states)[(size_t)wave * 64 + lane];
    const float x = v.x;
    const float y = v.y;

    // exp(-d2 / 0.01) = exp2(-d2 * 100 * log2(e))
    const float NEG_C = -144.26950408889634f;  // -(1/0.01)*log2(e)

    float acc = 0.0f;
#pragma unroll
    for (int j = 0; j < 64; ++j) {
        const float sx = __int_as_float(__builtin_amdgcn_readlane(__float_as_int(x), j));
        const float sy = __int_as_float(__builtin_amdgcn_readlane(__float_as_int(y), j));
        const float dx = x - sx;
        const float dy = y - sy;
        float d2 = dx * dx;
        d2 = fmaf(dy, dy, d2);
        acc += fast_exp2(d2 * NEG_C);
    }

    // Wave-wide sum (64 lanes).
#pragma unroll
    for (int off = 32; off > 0; off >>= 1) {
        acc += __shfl_xor(acc, off, 64);
    }

    if (lane == 0) {
        // acc = sum over all (i,j) incl. diagonal (64 ones).
        // strict lower-tri sum = (acc - 64) / 2; scale by WEIGHT=10.
        out[wave] = 10.0f * 0.5f * (acc - 64.0f);
    }
}

extern "C" void kernel_launch(void* const* d_in, const int* in_sizes, int n_in,
                              void* d_out, int out_size, void* d_ws, size_t ws_size,
                              hipStream_t stream) {
    const float* states = (const float*)d_in[0];
    float* out = (float*)d_out;

    const int total = in_sizes[0] / 256;  // B*H rows of 256 floats
    const int threads = 256;              // 4 waves per block
    const int waves_per_block = threads / 64;
    const int grid = (total + waves_per_block - 1) / waves_per_block;

    inter_agent_penalty_kernel<<<grid, threads, 0, stream>>>(states, out, total);
}

// Round 4
// 61.641 us; speedup vs baseline: 1.0497x; 1.0497x over previous
//
#include <hip/hip_runtime.h>

// InterAgentSoftPenalty: B=32, H=256, N=64, D=4N=256.
// pos[b,h,n,:] = states[b,h,n*4 + {0,1}]; out[b,h] = 10 * sum_{i>j} exp(-d2/0.01)
//
// One wave per (b,h) row; lane i holds pos_i (one coalesced float4 load).
// Pair symmetry via lane rotation: for k=1..31, pairs (i, (i+k)&63) cover
// each unordered pair at circular offset k exactly once (64*31 = 1984 pairs);
// k=32 covers its 32 pairs twice -> half weight (+32). 1984+32 = 2016 = C(64,2).
// => out = 10 * wavesum, no diagonal correction, 32 exps/lane instead of 64.
//
// Coordinates pre-scaled by sqrt(100*log2(e)) so exp(-d2/0.01) = exp2(-D2)
// with D2 in scaled space; the negation folds into v_exp_f32's -src modifier.

#ifndef __has_builtin
#define __has_builtin(x) 0
#endif

__device__ __forceinline__ float fast_exp2(float x) {
#if __has_builtin(__builtin_amdgcn_exp2f)
    return __builtin_amdgcn_exp2f(x);
#else
    return exp2f(x);
#endif
}

__global__ __launch_bounds__(256) void inter_agent_penalty_kernel(
    const float* __restrict__ states,  // [total][256] = [total][64 agents][4]
    float* __restrict__ out,           // [total]
    int total) {
    const int gtid = blockIdx.x * blockDim.x + threadIdx.x;
    const int wave = gtid >> 6;
    const int lane = threadIdx.x & 63;
    if (wave >= total) return;

    // Coalesced: lane i reads float4 #i of this row; (x,y) = first two comps.
    const float4 v = reinterpret_cast<const float4*>(states)[(size_t)wave * 64 + lane];

    // Pre-scale: S = sqrt(100 * log2(e)); exp(-d2/0.01) = exp2(-(S*dx)^2 - (S*dy)^2)
    const float S = 12.0112241f;  // sqrt(144.26950408889634)
    const float X = v.x * S;
    const float Y = v.y * S;

    const int laneB = lane << 2;  // byte address of own lane for ds_bpermute

    float acc = 0.0f;
#pragma unroll
    for (int k = 1; k <= 32; ++k) {
        const int addr = (laneB + (k << 2)) & 255;  // lane (i+k)&63, bytes
        const float sx = __int_as_float(__builtin_amdgcn_ds_bpermute(addr, __float_as_int(X)));
        const float sy = __int_as_float(__builtin_amdgcn_ds_bpermute(addr, __float_as_int(Y)));
        const float dx = X - sx;
        const float dy = Y - sy;
        const float d2 = fmaf(dy, dy, dx * dx);
        const float e = fast_exp2(-d2);
        acc += (k == 32) ? 0.5f * e : e;  // k=32 pairs counted twice
    }

    // Wave-wide sum (64 lanes).
#pragma unroll
    for (int off = 32; off > 0; off >>= 1) {
        acc += __shfl_xor(acc, off, 64);
    }

    if (lane == 0) {
        out[wave] = 10.0f * acc;  // acc already == strict lower-tri sum
    }
}

extern "C" void kernel_launch(void* const* d_in, const int* in_sizes, int n_in,
                              void* d_out, int out_size, void* d_ws, size_t ws_size,
                              hipStream_t stream) {
    const float* states = (const float*)d_in[0];
    float* out = (float*)d_out;

    const int total = in_sizes[0] / 256;  // B*H rows of 256 floats
    const int threads = 256;              // 4 waves per block
    const int waves_per_block = threads / 64;
    const int grid = (total + waves_per_block - 1) / waves_per_block;

    inter_agent_penalty_kernel<<<grid, threads, 0, stream>>>(states, out, total);
}

// Round 5
// 58.631 us; speedup vs baseline: 1.1036x; 1.0513x over previous
//
#include <hip/hip_runtime.h>

// InterAgentSoftPenalty: B=32, H=256, N=64, D=4N=256.
// pos[b,h,n,:] = states[b,h,n*4 + {0,1}]; out[b,h] = 10 * sum_{i>j} exp(-d2/0.01)
//
// One wave per (b,h) row; lane i holds pos_i (one coalesced float4 load).
// Pair symmetry via lane rotation: pairs (i,(i+k)&63) for k=1..31 cover each
// unordered pair once; k=32 covers its pairs twice -> half weight.
// 64*31 + 32 = 2016 = C(64,2). out = 10 * wavesum.
//
// Broadcast via LDS rotation reads (not ds_bpermute): each wave stages its 64
// scaled (x,y) pairs in LDS twice ([lane] and [lane+64], one ds_write2_b64),
// then row[k] is a plain float2 read -> compiler merges into ds_read2_b64.
// DS instrs/wave ~18 vs 70 for the bpermute version. Wave sum via DPP
// (row_shr 1/2/4/8 + row_bcast 15/31) -> zero DS in the reduction.

#ifndef __has_builtin
#define __has_builtin(x) 0
#endif

__device__ __forceinline__ float fast_exp2(float x) {
#if __has_builtin(__builtin_amdgcn_exp2f)
    return __builtin_amdgcn_exp2f(x);
#else
    return exp2f(x);
#endif
}

// DPP move: returns x shifted per CTRL; invalid source lanes read 0 (bound_ctrl=1).
template <int CTRL>
__device__ __forceinline__ float dpp_mov(float x) {
    return __int_as_float(
        __builtin_amdgcn_update_dpp(0, __float_as_int(x), CTRL, 0xF, 0xF, true));
}

__global__ __launch_bounds__(256) void inter_agent_penalty_kernel(
    const float* __restrict__ states,  // [total][256] = [total][64 agents][4]
    float* __restrict__ out,           // [total]
    int total) {
    __shared__ float2 buf[4][128];  // per-wave row, duplicated for wrap-free rotation

    const int wid = threadIdx.x >> 6;
    const int lane = threadIdx.x & 63;
    const int wave = blockIdx.x * 4 + wid;
    if (wave >= total) return;

    // Coalesced: lane i reads float4 #i of its row; (x,y) = first two comps.
    const float4 v = reinterpret_cast<const float4*>(states)[(size_t)wave * 64 + lane];

    // Pre-scale by sqrt(100*log2(e)): exp(-d2/0.01) = exp2(-(S dx)^2 - (S dy)^2)
    const float S = 12.0112241f;
    const float X = v.x * S;
    const float Y = v.y * S;

    const float2 p = make_float2(X, Y);
    buf[wid][lane] = p;        // compiler pairs these two stores
    buf[wid][lane + 64] = p;   // into one ds_write2_b64 (offsets 0, 64)
    __syncthreads();

    const float2* row = &buf[wid][lane];

    float acc = 0.0f;
#pragma unroll 16
    for (int k = 1; k <= 32; ++k) {
        const float2 q = row[k];  // adjacent k's merge into ds_read2_b64
        const float dx = X - q.x;
        const float dy = Y - q.y;
        acc += fast_exp2(-fmaf(dy, dy, dx * dx));
    }
    // k=32 pairs are each counted twice across the wave -> net weight 1/2.
    {
        const float2 q = row[32];
        const float dx = X - q.x;
        const float dy = Y - q.y;
        acc -= 0.5f * fast_exp2(-fmaf(dy, dy, dx * dx));
    }

    // Wave-wide sum via DPP: prefix within 16-lane rows, then row broadcasts.
    acc += dpp_mov<0x111>(acc);  // row_shr:1
    acc += dpp_mov<0x112>(acc);  // row_shr:2
    acc += dpp_mov<0x114>(acc);  // row_shr:4
    acc += dpp_mov<0x118>(acc);  // row_shr:8   -> lane 15 of each row = row sum
    acc += dpp_mov<0x142>(acc);  // row_bcast:15 -> lane 31 = sum(0..31), lane 63 = sum(32..63)
    acc += dpp_mov<0x143>(acc);  // row_bcast:31 -> lane 63 = total

    if (lane == 63) {
        out[wave] = 10.0f * acc;
    }
}

extern "C" void kernel_launch(void* const* d_in, const int* in_sizes, int n_in,
                              void* d_out, int out_size, void* d_ws, size_t ws_size,
                              hipStream_t stream) {
    const float* states = (const float*)d_in[0];
    float* out = (float*)d_out;

    const int total = in_sizes[0] / 256;  // B*H rows of 256 floats
    const int threads = 256;              // 4 waves per block
    const int waves_per_block = threads / 64;
    const int grid = (total + waves_per_block - 1) / waves_per_block;

    inter_agent_penalty_kernel<<<grid, threads, 0, stream>>>(states, out, total);
}

// Round 6
// 58.101 us; speedup vs baseline: 1.1136x; 1.0091x over previous
//
#include <hip/hip_runtime.h>

// InterAgentSoftPenalty: B=32, H=256, N=64, D=4N=256.
// pos[b,h,n,:] = states[b,h,n*4 + {0,1}]; out[b,h] = 10 * sum_{i>j} exp(-d2/0.01)
//
// One wave per (b,h) row; lane i holds pos_i (one coalesced float4 load).
// Pair symmetry via lane rotation: pairs (i,(i+k)&63) for k=1..31 cover each
// unordered pair once; k=32 covers its pairs twice -> weight 0.5 (folded at
// compile time in the fully-unrolled body). 64*31 + 32 = 2016 = C(64,2).
// => exactly 32 v_exp_f32 per lane — one per unordered pair — the structural
// minimum. out = 10 * wavesum.
//
// Broadcast via wave-private LDS rotation reads: each wave stages its 64
// scaled (x,y) pairs duplicated ([lane], [lane+64]; one ds_write2_b64), then
// row[k] is a plain float2 read (merged into 16x ds_read2_b64, conflict-free:
// 2 lanes/bank). Wave sum via DPP (row_shr 1/2/4/8 + row_bcast 15/31): zero
// DS traffic in the reduction. Two accumulators break the serial add chain so
// the trans pipe (32 x 4cy) is the per-wave floor.

#ifndef __has_builtin
#define __has_builtin(x) 0
#endif

__device__ __forceinline__ float fast_exp2(float x) {
#if __has_builtin(__builtin_amdgcn_exp2f)
    return __builtin_amdgcn_exp2f(x);
#else
    return exp2f(x);
#endif
}

// DPP move: x shifted per CTRL; invalid source lanes contribute 0 (bound_ctrl=1).
template <int CTRL>
__device__ __forceinline__ float dpp_mov(float x) {
    return __int_as_float(
        __builtin_amdgcn_update_dpp(0, __float_as_int(x), CTRL, 0xF, 0xF, true));
}

__global__ __launch_bounds__(256) void inter_agent_penalty_kernel(
    const float* __restrict__ states,  // [total][256] = [total][64 agents][4]
    float* __restrict__ out,           // [total]
    int total) {
    __shared__ float2 buf[4][128];  // per-wave row, duplicated for wrap-free rotation

    const int wid = threadIdx.x >> 6;
    const int lane = threadIdx.x & 63;
    const int wave = blockIdx.x * 4 + wid;
    if (wave >= total) return;  // total % 4 == 0 in this problem (8192/4): no
                                // partial block, so no barrier divergence.

    // Coalesced: lane i reads float4 #i of its row; (x,y) = first two comps.
    const float4 v = reinterpret_cast<const float4*>(states)[(size_t)wave * 64 + lane];

    // Pre-scale by sqrt(100*log2(e)): exp(-d2/0.01) = exp2(-(S dx)^2 - (S dy)^2)
    const float S = 12.0112241f;
    const float X = v.x * S;
    const float Y = v.y * S;

    const float2 p = make_float2(X, Y);
    buf[wid][lane] = p;        // paired into one ds_write2_b64
    buf[wid][lane + 64] = p;
    __syncthreads();

    const float2* row = &buf[wid][lane];

    // Fully unrolled: 16x ds_read2_b64, 32 exps, k=32 weight folded to 0.5.
    float acc0 = 0.0f, acc1 = 0.0f;
#pragma unroll
    for (int k = 1; k <= 32; ++k) {
        const float2 q = row[k];
        const float dx = X - q.x;
        const float dy = Y - q.y;
        const float e = fast_exp2(-fmaf(dy, dy, dx * dx));
        const float w = (k == 32) ? 0.5f * e : e;  // compile-time fold
        if (k & 1) acc0 += w; else acc1 += w;
    }
    float acc = acc0 + acc1;

    // Wave-wide sum via DPP: prefix within 16-lane rows, then row broadcasts.
    acc += dpp_mov<0x111>(acc);  // row_shr:1
    acc += dpp_mov<0x112>(acc);  // row_shr:2
    acc += dpp_mov<0x114>(acc);  // row_shr:4
    acc += dpp_mov<0x118>(acc);  // row_shr:8   -> lane 15 of each row = row sum
    acc += dpp_mov<0x142>(acc);  // row_bcast:15 -> lane 31 += sum(0..15) etc.
    acc += dpp_mov<0x143>(acc);  // row_bcast:31 -> lane 63 = total

    if (lane == 63) {
        out[wave] = 10.0f * acc;
    }
}

extern "C" void kernel_launch(void* const* d_in, const int* in_sizes, int n_in,
                              void* d_out, int out_size, void* d_ws, size_t ws_size,
                              hipStream_t stream) {
    const float* states = (const float*)d_in[0];
    float* out = (float*)d_out;

    const int total = in_sizes[0] / 256;  // B*H rows of 256 floats
    const int threads = 256;              // 4 waves per block
    const int waves_per_block = threads / 64;
    const int grid = (total + waves_per_block - 1) / waves_per_block;

    inter_agent_penalty_kernel<<<grid, threads, 0, stream>>>(states, out, total);
}